// Round 5
// baseline (434.248 us; speedup 1.0000x reference)
//
#include <hip/hip_runtime.h>
#include <hip/hip_bf16.h>
#include <stdint.h>

#define Bn 8
#define Ln 1024
#define Dn 1024
#define Hn 16
#define HDn 64
#define Mn (Bn*Ln)   // 8192
#define Kn 1024

typedef __attribute__((ext_vector_type(8))) __bf16 bf16x8;
typedef __attribute__((ext_vector_type(4))) float f32x4;

__device__ __forceinline__ unsigned short f2bf(float f) {
    unsigned int u = __float_as_uint(f);
    unsigned int r = (u + 0x7fff + ((u >> 16) & 1)) >> 16;
    return (unsigned short)r;
}

__device__ __forceinline__ void gload_lds16(void* lds, const void* g) {
    __builtin_amdgcn_global_load_lds(
        (const __attribute__((address_space(1))) unsigned int*)g,
        (__attribute__((address_space(3))) unsigned int*)lds,
        16, 0, 0);
}

// ---------------- prep: fp32->bf16 converts + 5 weight transposes --
// blocks [0,16384): cvt (8192 per tensor); [16384,21504): transpose
__global__ void prep_kernel(const float* __restrict__ h,
                            const float* __restrict__ s,
                            const float* __restrict__ Wq,
                            const float* __restrict__ Wk,
                            const float* __restrict__ Wq2,
                            const float* __restrict__ Wk2,
                            const float* __restrict__ Wv,
                            unsigned short* __restrict__ ho,
                            unsigned short* __restrict__ so,
                            unsigned short* __restrict__ wcat4,
                            unsigned short* __restrict__ wtv) {
    __shared__ float tile[32][33];
    int bid = blockIdx.x;
    int t = threadIdx.x;
    if (bid < 16384) {
        const float* in = (bid >> 13) ? s : h;
        unsigned short* out = (bid >> 13) ? so : ho;
        size_t i = (((size_t)(bid & 8191)) * 256 + t) * 4;
        float4 f = *(const float4*)(in + i);
        ushort4 o;
        o.x = f2bf(f.x); o.y = f2bf(f.y); o.z = f2bf(f.z); o.w = f2bf(f.w);
        *(ushort4*)(out + i) = o;
        return;
    }
    int bid2 = bid - 16384;
    int z = bid2 >> 10, tl = bid2 & 1023;
    int bx = tl & 31, by = tl >> 5;
    const float* W; unsigned short* Wt;
    switch (z) {
        case 0: W = Wq;  Wt = wcat4;                 break;
        case 1: W = Wk;  Wt = wcat4 + 1024 * 1024;   break;
        case 2: W = Wq2; Wt = wcat4 + 2048 * 1024;   break;
        case 3: W = Wk2; Wt = wcat4 + 3072 * 1024;   break;
        default:W = Wv;  Wt = wtv;                   break;
    }
    int tx = t & 31, ty = t >> 5;
    int col = bx * 32 + tx;
    for (int i = 0; i < 32; i += 8)
        tile[ty + i][tx] = W[(size_t)(by * 32 + ty + i) * Dn + col];
    __syncthreads();
    int ok = by * 32 + tx;
    for (int i = 0; i < 32; i += 8)
        Wt[(size_t)(bx * 32 + ty + i) * Kn + ok] = f2bf(tile[tx][ty + i]);
}

// ---------------- shared GEMM mainloop (128x128 tile, BK=32) ------
// Paired-row LDS mapping: LDS = 64 phys rows x 128B (8 slots of 16B).
// Thread t stages: p=t>>3, q=t&7, q'=q^(p&7) -> logical m=2p+(q'>>2),
// k-chunk c=q'&3. Fragment read (m,c=lquad): phys row m>>1, slot
// ((m&1)*4+lquad)^((m>>1)&7). Conflict-free both directions.
__device__ __forceinline__ void gemm_mainloop(const unsigned short* __restrict__ A,
                                              const unsigned short* __restrict__ Bt,
                                              unsigned short* As, unsigned short* Bs,
                                              int m0, int n0, f32x4 acc[4][4]) {
    int t = threadIdx.x;
    int lane = t & 63, wave = t >> 6;
    int wm = (wave >> 1) * 64, wn = (wave & 1) * 64;
    int lrow = lane & 15, lquad = lane >> 4;

    int q2 = (t & 7) ^ ((t >> 3) & 7);
    int srow = ((t >> 3) << 1) | (q2 >> 2);
    int scol = (q2 & 3) * 8;
    const unsigned short* ap0 = A  + (size_t)(m0 + srow) * Kn + scol;
    const unsigned short* ap1 = A  + (size_t)(m0 + 64 + srow) * Kn + scol;
    const unsigned short* bp0 = Bt + (size_t)(n0 + srow) * Kn + scol;
    const unsigned short* bp1 = Bt + (size_t)(n0 + 64 + srow) * Kn + scol;

    int rslot8 = ((((lrow & 1) << 2) | lquad) ^ ((lrow >> 1) & 7)) * 8;
    int rbaseA = ((wm >> 1) + (lrow >> 1)) * 64;
    int rbaseB = ((wn >> 1) + (lrow >> 1)) * 64;

    for (int k0 = 0; k0 < Kn; k0 += 32) {
        gload_lds16(&As[t * 8],         ap0 + k0);
        gload_lds16(&As[(t + 256) * 8], ap1 + k0);
        gload_lds16(&Bs[t * 8],         bp0 + k0);
        gload_lds16(&Bs[(t + 256) * 8], bp1 + k0);
        __syncthreads();
        bf16x8 af[4], bfr[4];
        for (int i = 0; i < 4; i++)
            af[i] = *(const bf16x8*)&As[rbaseA + i * 8 * 64 + rslot8];
        for (int j = 0; j < 4; j++)
            bfr[j] = *(const bf16x8*)&Bs[rbaseB + j * 8 * 64 + rslot8];
        for (int i = 0; i < 4; i++)
            for (int j = 0; j < 4; j++)
                acc[i][j] = __builtin_amdgcn_mfma_f32_16x16x32_bf16(af[i], bfr[j], acc[i][j], 0, 0, 0);
        __syncthreads();
    }
}

// ---- all 5 projections in ONE dispatch (2560 linearized blocks) ----
__launch_bounds__(256, 4)
__global__ void gemm_all_kernel(const unsigned short* __restrict__ hb,
                                const unsigned short* __restrict__ sb,
                                const unsigned short* __restrict__ wcat4,
                                const unsigned short* __restrict__ wtv,
                                const float* __restrict__ bq,
                                const float* __restrict__ bk,
                                const float* __restrict__ bq2,
                                const float* __restrict__ bk2,
                                const float* __restrict__ bv,
                                unsigned short* __restrict__ qbuf,
                                unsigned short* __restrict__ kbuf,
                                unsigned short* __restrict__ q2buf,
                                unsigned short* __restrict__ k2buf,
                                unsigned short* __restrict__ vtbuf) {
    __shared__ __align__(16) unsigned short As[128 * 32];
    __shared__ __align__(16) unsigned short Bs[128 * 32];
    int bid = blockIdx.x;
    int t = threadIdx.x;
    int lane = t & 63, wave = t >> 6;
    int wm = (wave >> 1) * 64, wn = (wave & 1) * 64;
    int lrow = lane & 15, lquad = lane >> 4;
    f32x4 acc[4][4] = {};

    if (bid < 2048) {
        int n0 = (bid & 31) * 128, m0 = (bid >> 5) * 128;
        int region = n0 >> 10;
        const unsigned short* A = (region == 3) ? sb : hb;
        gemm_mainloop(A, wcat4, As, Bs, m0, n0, acc);

        const float* bp = region == 0 ? bq : region == 1 ? bk : region == 2 ? bq2 : bk2;
        unsigned short* dp = region == 0 ? qbuf : region == 1 ? kbuf : region == 2 ? q2buf : k2buf;
        float sc = (region == 0 || region == 2) ? 0.125f : 1.0f;
        for (int j = 0; j < 4; j++) {
            int gn = (n0 & 1023) + wn + j * 16 + lrow;
            float bv_ = bp[gn];
            int h = gn >> 6, hd = gn & 63;
            for (int i = 0; i < 4; i++)
                for (int r = 0; r < 4; r++) {
                    int gm = m0 + wm + i * 16 + lquad * 4 + r;
                    int b = gm >> 10, ll = gm & 1023;
                    dp[((size_t)(b * Hn + h) * Ln + ll) * HDn + hd] = f2bf((acc[i][j][r] + bv_) * sc);
                }
        }
    } else {
        int b2 = bid - 2048;
        int n0 = (b2 & 63) * 128;     // token tile
        int m0 = (b2 >> 6) * 128;     // channel tile
        gemm_mainloop(wtv, hb, As, Bs, m0, n0, acc);

        for (int j = 0; j < 4; j++) {
            int gn = n0 + wn + j * 16 + lrow;     // token
            int b = gn >> 10, l = gn & 1023;
            for (int i = 0; i < 4; i++)
                for (int r = 0; r < 4; r++) {
                    int gm = m0 + wm + i * 16 + lquad * 4 + r;   // channel
                    int h = gm >> 6, hd = gm & 63;
                    vtbuf[((size_t)(b * Hn + h) * HDn + hd) * Ln + l] = f2bf(acc[i][j][r] + bv[gm]);
                }
        }
    }
}

// ---------------- flash attention, one-pass (deferred normalization)
// Q-tile 128/block (2 row-tiles/wave). LDS 16B chunks XOR-swizzled by row&7.
__launch_bounds__(256, 4)
__global__ void attn_kernel(const unsigned short* __restrict__ qb,
                            const unsigned short* __restrict__ kb,
                            const unsigned short* __restrict__ q2b,
                            const unsigned short* __restrict__ k2b,
                            const unsigned short* __restrict__ vtb,
                            const float* __restrict__ mask,
                            float* __restrict__ out) {
    __shared__ __align__(16) unsigned short Ks[64 * 64];
    __shared__ __align__(16) unsigned short K2s[64 * 64];
    __shared__ __align__(16) unsigned short VTs[64 * 64];
    __shared__ __align__(16) unsigned short Ps[4 * 32 * 64];

    int bh = blockIdx.x;
    int qt = blockIdx.y;
    int b = bh >> 4;
    int t = threadIdx.x;
    int lane = t & 63, wave = t >> 6;
    int lrow = lane & 15, lquad = lane >> 4;
    int qbase = qt * 128 + wave * 32;

    bf16x8 qf[2][2], q2f[2][2];
    for (int rt = 0; rt < 2; rt++)
        for (int kk = 0; kk < 2; kk++) {
            size_t off = ((size_t)bh * Ln + qbase + rt * 16 + lrow) * HDn + kk * 32 + lquad * 8;
            qf[rt][kk]  = *(const bf16x8*)(qb + off);
            q2f[rt][kk] = *(const bf16x8*)(q2b + off);
        }

    f32x4 O[2][4] = {};
    f32x4 lsum[2] = {};

    int srow = t >> 3;
    int sc8 = ((t & 7) ^ (srow & 7)) * 8;
    const float* maskb = mask + (size_t)b * Ln;
    int rph = lrow & 7;
    unsigned short* pw = &Ps[wave * 32 * 64];

    for (int kt = 0; kt < 16; kt++) {
        int key0 = kt * 64;
        gload_lds16(&Ks[t * 8],          kb  + ((size_t)bh * Ln + key0 + srow) * HDn + sc8);
        gload_lds16(&Ks[(t + 256) * 8],  kb  + ((size_t)bh * Ln + key0 + 32 + srow) * HDn + sc8);
        gload_lds16(&K2s[t * 8],         k2b + ((size_t)bh * Ln + key0 + srow) * HDn + sc8);
        gload_lds16(&K2s[(t + 256) * 8], k2b + ((size_t)bh * Ln + key0 + 32 + srow) * HDn + sc8);
        gload_lds16(&VTs[t * 8],         vtb + ((size_t)bh * HDn + srow) * Ln + key0 + sc8);
        gload_lds16(&VTs[(t + 256) * 8], vtb + ((size_t)bh * HDn + 32 + srow) * Ln + key0 + sc8);
        __syncthreads();

        f32x4 S[2][4];
        for (int j = 0; j < 4; j++) {
            float mk = maskb[key0 + j * 16 + lrow];
            S[0][j] = (f32x4){mk, mk, mk, mk};
            S[1][j] = S[0][j];
        }
        for (int kk = 0; kk < 2; kk++) {
            for (int j = 0; j < 4; j++) {
                bf16x8 kf = *(const bf16x8*)&Ks[(j * 16 + lrow) * 64 + ((kk * 4 + lquad) ^ rph) * 8];
                S[0][j] = __builtin_amdgcn_mfma_f32_16x16x32_bf16(qf[0][kk], kf, S[0][j], 0, 0, 0);
                S[1][j] = __builtin_amdgcn_mfma_f32_16x16x32_bf16(qf[1][kk], kf, S[1][j], 0, 0, 0);
            }
            for (int j = 0; j < 4; j++) {
                bf16x8 kf = *(const bf16x8*)&K2s[(j * 16 + lrow) * 64 + ((kk * 4 + lquad) ^ rph) * 8];
                S[0][j] = __builtin_amdgcn_mfma_f32_16x16x32_bf16(q2f[0][kk], kf, S[0][j], 0, 0, 0);
                S[1][j] = __builtin_amdgcn_mfma_f32_16x16x32_bf16(q2f[1][kk], kf, S[1][j], 0, 0, 0);
            }
        }

        for (int rt = 0; rt < 2; rt++)
            for (int j = 0; j < 4; j++)
                for (int r = 0; r < 4; r++) {
                    float e = __expf(S[rt][j][r]);
                    lsum[rt][r] += e;
                    int pr = rt * 16 + lquad * 4 + r;
                    int cw = (j * 2 + (lrow >> 3)) ^ (pr & 7);
                    pw[pr * 64 + cw * 8 + (lrow & 7)] = f2bf(e);
                }

        for (int kk = 0; kk < 2; kk++) {
            bf16x8 pf0 = *(const bf16x8*)&pw[lrow * 64 + ((kk * 4 + lquad) ^ rph) * 8];
            bf16x8 pf1 = *(const bf16x8*)&pw[(16 + lrow) * 64 + ((kk * 4 + lquad) ^ rph) * 8];
            for (int j = 0; j < 4; j++) {
                bf16x8 vf = *(const bf16x8*)&VTs[(j * 16 + lrow) * 64 + ((kk * 4 + lquad) ^ rph) * 8];
                O[0][j] = __builtin_amdgcn_mfma_f32_16x16x32_bf16(pf0, vf, O[0][j], 0, 0, 0);
                O[1][j] = __builtin_amdgcn_mfma_f32_16x16x32_bf16(pf1, vf, O[1][j], 0, 0, 0);
            }
        }
        __syncthreads();
    }

    for (int rt = 0; rt < 2; rt++)
        for (int r = 0; r < 4; r++) {
            float s = lsum[rt][r];
            for (int d = 1; d < 16; d <<= 1)
                s += __shfl_xor(s, d, 64);
            lsum[rt][r] = s;
        }

    int h = bh & 15;
    for (int rt = 0; rt < 2; rt++)
        for (int r = 0; r < 4; r++) {
            float rl = 1.0f / lsum[rt][r];
            int ql = qbase + rt * 16 + lquad * 4 + r;
            for (int j = 0; j < 4; j++)
                out[((size_t)b * Ln + ql) * Dn + h * HDn + j * 16 + lrow] = O[rt][j][r] * rl;
        }
}

extern "C" void kernel_launch(void* const* d_in, const int* in_sizes, int n_in,
                              void* d_out, int out_size, void* d_ws, size_t ws_size,
                              hipStream_t stream) {
    const float* hidden = (const float*)d_in[0];
    const float* mask   = (const float*)d_in[1];
    const float* source = (const float*)d_in[2];
    const float* Wq  = (const float*)d_in[3];
    const float* bq  = (const float*)d_in[4];
    const float* Wk  = (const float*)d_in[5];
    const float* bk  = (const float*)d_in[6];
    const float* Wv  = (const float*)d_in[7];
    const float* bv  = (const float*)d_in[8];
    const float* Wq2 = (const float*)d_in[9];
    const float* bq2 = (const float*)d_in[10];
    const float* Wk2 = (const float*)d_in[11];
    const float* bk2 = (const float*)d_in[12];
    float* out = (float*)d_out;

    char* ws = (char*)d_ws;
    const size_t act_sz = (size_t)Mn * Dn * 2;   // 16 MB
    const size_t w_sz   = (size_t)Kn * Dn * 2;   // 2 MB
    unsigned short* hb    = (unsigned short*)ws; ws += act_sz;
    unsigned short* sb    = (unsigned short*)ws; ws += act_sz;
    unsigned short* wcat4 = (unsigned short*)ws; ws += 4 * w_sz;
    unsigned short* wtv   = (unsigned short*)ws; ws += w_sz;
    unsigned short* qbuf  = (unsigned short*)ws; ws += act_sz;
    unsigned short* kbuf  = (unsigned short*)ws; ws += act_sz;
    unsigned short* q2buf = (unsigned short*)ws; ws += act_sz;
    unsigned short* k2buf = (unsigned short*)ws; ws += act_sz;
    unsigned short* vtbuf = (unsigned short*)ws; ws += act_sz;

    // 1) prep: converts + transposes, one dispatch
    prep_kernel<<<21504, 256, 0, stream>>>(hidden, source, Wq, Wk, Wq2, Wk2, Wv,
                                           hb, sb, wcat4, wtv);

    // 2) all 5 projections, one dispatch
    gemm_all_kernel<<<2560, 256, 0, stream>>>(hb, sb, wcat4, wtv,
                                              bq, bk, bq2, bk2, bv,
                                              qbuf, kbuf, q2buf, k2buf, vtbuf);

    // 3) attention (Q-tile 128, one-pass softmax)
    dim3 agrid(Bn * Hn, Ln / 128);               // (128, 8)
    attn_kernel<<<agrid, 256, 0, stream>>>(qbuf, kbuf, q2buf, k2buf, vtbuf, mask, out);
}

// Round 6
// 340.266 us; speedup vs baseline: 1.2762x; 1.2762x over previous
//
#include <hip/hip_runtime.h>
#include <hip/hip_bf16.h>
#include <stdint.h>

#define Bn 8
#define Ln 1024
#define Dn 1024
#define Hn 16
#define HDn 64
#define Mn (Bn*Ln)   // 8192
#define Kn 1024

typedef __attribute__((ext_vector_type(8))) __bf16 bf16x8;
typedef __attribute__((ext_vector_type(4))) float f32x4;

__device__ __forceinline__ unsigned short f2bf(float f) {
    unsigned int u = __float_as_uint(f);
    unsigned int r = (u + 0x7fff + ((u >> 16) & 1)) >> 16;
    return (unsigned short)r;
}

__device__ __forceinline__ void gload_lds16(void* lds, const void* g) {
    __builtin_amdgcn_global_load_lds(
        (const __attribute__((address_space(1))) unsigned int*)g,
        (__attribute__((address_space(3))) unsigned int*)lds,
        16, 0, 0);
}

// ---------------- prep: fp32->bf16 converts + 5 weight transposes --
__global__ void prep_kernel(const float* __restrict__ h,
                            const float* __restrict__ s,
                            const float* __restrict__ Wq,
                            const float* __restrict__ Wk,
                            const float* __restrict__ Wq2,
                            const float* __restrict__ Wk2,
                            const float* __restrict__ Wv,
                            unsigned short* __restrict__ ho,
                            unsigned short* __restrict__ so,
                            unsigned short* __restrict__ wcat4,
                            unsigned short* __restrict__ wtv) {
    __shared__ float tile[32][33];
    int bid = blockIdx.x;
    int t = threadIdx.x;
    if (bid < 16384) {
        const float* in = (bid >> 13) ? s : h;
        unsigned short* out = (bid >> 13) ? so : ho;
        size_t i = (((size_t)(bid & 8191)) * 256 + t) * 4;
        float4 f = *(const float4*)(in + i);
        ushort4 o;
        o.x = f2bf(f.x); o.y = f2bf(f.y); o.z = f2bf(f.z); o.w = f2bf(f.w);
        *(ushort4*)(out + i) = o;
        return;
    }
    int bid2 = bid - 16384;
    int z = bid2 >> 10, tl = bid2 & 1023;
    int bx = tl & 31, by = tl >> 5;
    const float* W; unsigned short* Wt;
    switch (z) {
        case 0: W = Wq;  Wt = wcat4;                 break;
        case 1: W = Wk;  Wt = wcat4 + 1024 * 1024;   break;
        case 2: W = Wq2; Wt = wcat4 + 2048 * 1024;   break;
        case 3: W = Wk2; Wt = wcat4 + 3072 * 1024;   break;
        default:W = Wv;  Wt = wtv;                   break;
    }
    int tx = t & 31, ty = t >> 5;
    int col = bx * 32 + tx;
    for (int i = 0; i < 32; i += 8)
        tile[ty + i][tx] = W[(size_t)(by * 32 + ty + i) * Dn + col];
    __syncthreads();
    int ok = by * 32 + tx;
    for (int i = 0; i < 32; i += 8)
        Wt[(size_t)(bx * 32 + ty + i) * Kn + ok] = f2bf(tile[tx][ty + i]);
}

// ---------------- shared GEMM mainloop (128x128 tile, BK=64) ------
// 16 K-iterations, 32 MFMAs per barrier pair (halves barrier-drain
// events vs BK=32). Rows are 128B; 16B chunk c of row r stored at
// slot c^(r&7) -> balanced banks both directions (attn-style swizzle,
// measured 0 conflicts).
__device__ __forceinline__ void gemm_mainloop(const unsigned short* __restrict__ A,
                                              const unsigned short* __restrict__ Bt,
                                              unsigned short* As, unsigned short* Bs,
                                              int m0, int n0, f32x4 acc[4][4]) {
    int t = threadIdx.x;
    int lane = t & 63, wave = t >> 6;
    int wm = (wave >> 1) * 64, wn = (wave & 1) * 64;
    int lrow = lane & 15, lquad = lane >> 4;

    int srow = t >> 3;                        // 0..31
    int sc8 = ((t & 7) ^ (srow & 7)) * 8;     // swizzled chunk offset
    const unsigned short* ap = A  + (size_t)(m0 + srow) * Kn + sc8;
    const unsigned short* bp = Bt + (size_t)(n0 + srow) * Kn + sc8;
    int rph = lrow & 7;

    for (int k0 = 0; k0 < Kn; k0 += 64) {
        for (int s = 0; s < 4; s++) {
            gload_lds16(&As[(t + 256 * s) * 8], ap + (size_t)(32 * s) * Kn + k0);
            gload_lds16(&Bs[(t + 256 * s) * 8], bp + (size_t)(32 * s) * Kn + k0);
        }
        __syncthreads();
        for (int kk = 0; kk < 2; kk++) {
            bf16x8 af[4], bfr[4];
            for (int i = 0; i < 4; i++)
                af[i] = *(const bf16x8*)&As[(wm + i * 16 + lrow) * 64 + ((kk * 4 + lquad) ^ rph) * 8];
            for (int j = 0; j < 4; j++)
                bfr[j] = *(const bf16x8*)&Bs[(wn + j * 16 + lrow) * 64 + ((kk * 4 + lquad) ^ rph) * 8];
            for (int i = 0; i < 4; i++)
                for (int j = 0; j < 4; j++)
                    acc[i][j] = __builtin_amdgcn_mfma_f32_16x16x32_bf16(af[i], bfr[j], acc[i][j], 0, 0, 0);
        }
        __syncthreads();
    }
}

// ---- all 5 projections in ONE dispatch (2560 linearized blocks) ----
__launch_bounds__(256, 3)
__global__ void gemm_all_kernel(const unsigned short* __restrict__ hb,
                                const unsigned short* __restrict__ sb,
                                const unsigned short* __restrict__ wcat4,
                                const unsigned short* __restrict__ wtv,
                                const float* __restrict__ bq,
                                const float* __restrict__ bk,
                                const float* __restrict__ bq2,
                                const float* __restrict__ bk2,
                                const float* __restrict__ bv,
                                unsigned short* __restrict__ qbuf,
                                unsigned short* __restrict__ kbuf,
                                unsigned short* __restrict__ q2buf,
                                unsigned short* __restrict__ k2buf,
                                unsigned short* __restrict__ vtbuf) {
    __shared__ __align__(16) unsigned short As[128 * 64];
    __shared__ __align__(16) unsigned short Bs[128 * 64];
    int bid = blockIdx.x;
    int t = threadIdx.x;
    int lane = t & 63, wave = t >> 6;
    int wm = (wave >> 1) * 64, wn = (wave & 1) * 64;
    int lrow = lane & 15, lquad = lane >> 4;
    f32x4 acc[4][4] = {};

    if (bid < 2048) {
        int n0 = (bid & 31) * 128, m0 = (bid >> 5) * 128;
        int region = n0 >> 10;
        const unsigned short* A = (region == 3) ? sb : hb;
        gemm_mainloop(A, wcat4, As, Bs, m0, n0, acc);

        const float* bp = region == 0 ? bq : region == 1 ? bk : region == 2 ? bq2 : bk2;
        unsigned short* dp = region == 0 ? qbuf : region == 1 ? kbuf : region == 2 ? q2buf : k2buf;
        float sc = (region == 0 || region == 2) ? 0.125f : 1.0f;
        for (int j = 0; j < 4; j++) {
            int gn = (n0 & 1023) + wn + j * 16 + lrow;
            float bv_ = bp[gn];
            int h = gn >> 6, hd = gn & 63;
            for (int i = 0; i < 4; i++)
                for (int r = 0; r < 4; r++) {
                    int gm = m0 + wm + i * 16 + lquad * 4 + r;
                    int b = gm >> 10, ll = gm & 1023;
                    dp[((size_t)(b * Hn + h) * Ln + ll) * HDn + hd] = f2bf((acc[i][j][r] + bv_) * sc);
                }
        }
    } else {
        int b2 = bid - 2048;
        int n0 = (b2 & 63) * 128;     // token tile
        int m0 = (b2 >> 6) * 128;     // channel tile
        gemm_mainloop(wtv, hb, As, Bs, m0, n0, acc);

        for (int j = 0; j < 4; j++) {
            int gn = n0 + wn + j * 16 + lrow;     // token
            int b = gn >> 10, l = gn & 1023;
            for (int i = 0; i < 4; i++)
                for (int r = 0; r < 4; r++) {
                    int gm = m0 + wm + i * 16 + lquad * 4 + r;   // channel
                    int h = gm >> 6, hd = gm & 63;
                    vtbuf[((size_t)(b * Hn + h) * HDn + hd) * Ln + l] = f2bf(acc[i][j][r] + bv[gm]);
                }
        }
    }
}

// ---------------- flash attention, one-pass (deferred normalization)
// Q-tile 128/block (2 row-tiles/wave). LDS 16B chunks XOR-swizzled by row&7.
// NOTE: bounds(256,3) is the L2-locality sweet spot — (256,4) makes the
// whole grid co-resident and thrashes L2 (FETCH 69->347 MB, r5 regression).
__launch_bounds__(256, 3)
__global__ void attn_kernel(const unsigned short* __restrict__ qb,
                            const unsigned short* __restrict__ kb,
                            const unsigned short* __restrict__ q2b,
                            const unsigned short* __restrict__ k2b,
                            const unsigned short* __restrict__ vtb,
                            const float* __restrict__ mask,
                            float* __restrict__ out) {
    __shared__ __align__(16) unsigned short Ks[64 * 64];
    __shared__ __align__(16) unsigned short K2s[64 * 64];
    __shared__ __align__(16) unsigned short VTs[64 * 64];
    __shared__ __align__(16) unsigned short Ps[4 * 32 * 64];

    int bh = blockIdx.x;
    int qt = blockIdx.y;
    int b = bh >> 4;
    int t = threadIdx.x;
    int lane = t & 63, wave = t >> 6;
    int lrow = lane & 15, lquad = lane >> 4;
    int qbase = qt * 128 + wave * 32;

    bf16x8 qf[2][2], q2f[2][2];
    for (int rt = 0; rt < 2; rt++)
        for (int kk = 0; kk < 2; kk++) {
            size_t off = ((size_t)bh * Ln + qbase + rt * 16 + lrow) * HDn + kk * 32 + lquad * 8;
            qf[rt][kk]  = *(const bf16x8*)(qb + off);
            q2f[rt][kk] = *(const bf16x8*)(q2b + off);
        }

    f32x4 O[2][4] = {};
    f32x4 lsum[2] = {};

    int srow = t >> 3;
    int sc8 = ((t & 7) ^ (srow & 7)) * 8;
    const float* maskb = mask + (size_t)b * Ln;
    int rph = lrow & 7;
    unsigned short* pw = &Ps[wave * 32 * 64];

    for (int kt = 0; kt < 16; kt++) {
        int key0 = kt * 64;
        gload_lds16(&Ks[t * 8],          kb  + ((size_t)bh * Ln + key0 + srow) * HDn + sc8);
        gload_lds16(&Ks[(t + 256) * 8],  kb  + ((size_t)bh * Ln + key0 + 32 + srow) * HDn + sc8);
        gload_lds16(&K2s[t * 8],         k2b + ((size_t)bh * Ln + key0 + srow) * HDn + sc8);
        gload_lds16(&K2s[(t + 256) * 8], k2b + ((size_t)bh * Ln + key0 + 32 + srow) * HDn + sc8);
        gload_lds16(&VTs[t * 8],         vtb + ((size_t)bh * HDn + srow) * Ln + key0 + sc8);
        gload_lds16(&VTs[(t + 256) * 8], vtb + ((size_t)bh * HDn + 32 + srow) * Ln + key0 + sc8);
        __syncthreads();

        f32x4 S[2][4];
        for (int j = 0; j < 4; j++) {
            float mk = maskb[key0 + j * 16 + lrow];
            S[0][j] = (f32x4){mk, mk, mk, mk};
            S[1][j] = S[0][j];
        }
        for (int kk = 0; kk < 2; kk++) {
            for (int j = 0; j < 4; j++) {
                bf16x8 kf = *(const bf16x8*)&Ks[(j * 16 + lrow) * 64 + ((kk * 4 + lquad) ^ rph) * 8];
                S[0][j] = __builtin_amdgcn_mfma_f32_16x16x32_bf16(qf[0][kk], kf, S[0][j], 0, 0, 0);
                S[1][j] = __builtin_amdgcn_mfma_f32_16x16x32_bf16(qf[1][kk], kf, S[1][j], 0, 0, 0);
            }
            for (int j = 0; j < 4; j++) {
                bf16x8 kf = *(const bf16x8*)&K2s[(j * 16 + lrow) * 64 + ((kk * 4 + lquad) ^ rph) * 8];
                S[0][j] = __builtin_amdgcn_mfma_f32_16x16x32_bf16(q2f[0][kk], kf, S[0][j], 0, 0, 0);
                S[1][j] = __builtin_amdgcn_mfma_f32_16x16x32_bf16(q2f[1][kk], kf, S[1][j], 0, 0, 0);
            }
        }

        for (int rt = 0; rt < 2; rt++)
            for (int j = 0; j < 4; j++)
                for (int r = 0; r < 4; r++) {
                    float e = __expf(S[rt][j][r]);
                    lsum[rt][r] += e;
                    int pr = rt * 16 + lquad * 4 + r;
                    int cw = (j * 2 + (lrow >> 3)) ^ (pr & 7);
                    pw[pr * 64 + cw * 8 + (lrow & 7)] = f2bf(e);
                }

        for (int kk = 0; kk < 2; kk++) {
            bf16x8 pf0 = *(const bf16x8*)&pw[lrow * 64 + ((kk * 4 + lquad) ^ rph) * 8];
            bf16x8 pf1 = *(const bf16x8*)&pw[(16 + lrow) * 64 + ((kk * 4 + lquad) ^ rph) * 8];
            for (int j = 0; j < 4; j++) {
                bf16x8 vf = *(const bf16x8*)&VTs[(j * 16 + lrow) * 64 + ((kk * 4 + lquad) ^ rph) * 8];
                O[0][j] = __builtin_amdgcn_mfma_f32_16x16x32_bf16(pf0, vf, O[0][j], 0, 0, 0);
                O[1][j] = __builtin_amdgcn_mfma_f32_16x16x32_bf16(pf1, vf, O[1][j], 0, 0, 0);
            }
        }
        __syncthreads();
    }

    for (int rt = 0; rt < 2; rt++)
        for (int r = 0; r < 4; r++) {
            float s = lsum[rt][r];
            for (int d = 1; d < 16; d <<= 1)
                s += __shfl_xor(s, d, 64);
            lsum[rt][r] = s;
        }

    int h = bh & 15;
    for (int rt = 0; rt < 2; rt++)
        for (int r = 0; r < 4; r++) {
            float rl = 1.0f / lsum[rt][r];
            int ql = qbase + rt * 16 + lquad * 4 + r;
            for (int j = 0; j < 4; j++)
                out[((size_t)b * Ln + ql) * Dn + h * HDn + j * 16 + lrow] = O[rt][j][r] * rl;
        }
}

extern "C" void kernel_launch(void* const* d_in, const int* in_sizes, int n_in,
                              void* d_out, int out_size, void* d_ws, size_t ws_size,
                              hipStream_t stream) {
    const float* hidden = (const float*)d_in[0];
    const float* mask   = (const float*)d_in[1];
    const float* source = (const float*)d_in[2];
    const float* Wq  = (const float*)d_in[3];
    const float* bq  = (const float*)d_in[4];
    const float* Wk  = (const float*)d_in[5];
    const float* bk  = (const float*)d_in[6];
    const float* Wv  = (const float*)d_in[7];
    const float* bv  = (const float*)d_in[8];
    const float* Wq2 = (const float*)d_in[9];
    const float* bq2 = (const float*)d_in[10];
    const float* Wk2 = (const float*)d_in[11];
    const float* bk2 = (const float*)d_in[12];
    float* out = (float*)d_out;

    char* ws = (char*)d_ws;
    const size_t act_sz = (size_t)Mn * Dn * 2;   // 16 MB
    const size_t w_sz   = (size_t)Kn * Dn * 2;   // 2 MB
    unsigned short* hb    = (unsigned short*)ws; ws += act_sz;
    unsigned short* sb    = (unsigned short*)ws; ws += act_sz;
    unsigned short* wcat4 = (unsigned short*)ws; ws += 4 * w_sz;
    unsigned short* wtv   = (unsigned short*)ws; ws += w_sz;
    unsigned short* qbuf  = (unsigned short*)ws; ws += act_sz;
    unsigned short* kbuf  = (unsigned short*)ws; ws += act_sz;
    unsigned short* q2buf = (unsigned short*)ws; ws += act_sz;
    unsigned short* k2buf = (unsigned short*)ws; ws += act_sz;
    unsigned short* vtbuf = (unsigned short*)ws; ws += act_sz;

    // 1) prep: converts + transposes, one dispatch
    prep_kernel<<<21504, 256, 0, stream>>>(hidden, source, Wq, Wk, Wq2, Wk2, Wv,
                                           hb, sb, wcat4, wtv);

    // 2) all 5 projections, one dispatch (BK=64 mainloop)
    gemm_all_kernel<<<2560, 256, 0, stream>>>(hb, sb, wcat4, wtv,
                                              bq, bk, bq2, bk2, bv,
                                              qbuf, kbuf, q2buf, k2buf, vtbuf);

    // 3) attention (Q-tile 128, one-pass softmax)
    dim3 agrid(Bn * Hn, Ln / 128);               // (128, 8)
    attn_kernel<<<agrid, 256, 0, stream>>>(qbuf, kbuf, q2buf, k2buf, vtbuf, mask, out);
}

// Round 7
// 319.564 us; speedup vs baseline: 1.3589x; 1.0648x over previous
//
#include <hip/hip_runtime.h>
#include <hip/hip_bf16.h>
#include <stdint.h>

#define Bn 8
#define Ln 1024
#define Dn 1024
#define Hn 16
#define HDn 64
#define Mn (Bn*Ln)   // 8192
#define Kn 1024

typedef __attribute__((ext_vector_type(8))) __bf16 bf16x8;
typedef __attribute__((ext_vector_type(4))) __bf16 bf16x4;
typedef __attribute__((ext_vector_type(4))) short s16x4;
typedef __attribute__((ext_vector_type(4))) float f32x4;

__device__ __forceinline__ unsigned short f2bf(float f) {
    unsigned int u = __float_as_uint(f);
    unsigned int r = (u + 0x7fff + ((u >> 16) & 1)) >> 16;
    return (unsigned short)r;
}

__device__ __forceinline__ f32x4 mfma16_bf16(bf16x4 a, s16x4 b, f32x4 c) {
#if __has_builtin(__builtin_amdgcn_mfma_f32_16x16x16_bf16)
    return __builtin_amdgcn_mfma_f32_16x16x16_bf16(a, __builtin_bit_cast(bf16x4, b), c, 0, 0, 0);
#else
    return __builtin_amdgcn_mfma_f32_16x16x16bf16_1k(__builtin_bit_cast(s16x4, a), b, c, 0, 0, 0);
#endif
}

__device__ __forceinline__ void gload_lds16(void* lds, const void* g) {
    __builtin_amdgcn_global_load_lds(
        (const __attribute__((address_space(1))) unsigned int*)g,
        (__attribute__((address_space(3))) unsigned int*)lds,
        16, 0, 0);
}

// ---------------- prep: fp32->bf16 converts + 5 weight transposes --
__global__ void prep_kernel(const float* __restrict__ h,
                            const float* __restrict__ s,
                            const float* __restrict__ Wq,
                            const float* __restrict__ Wk,
                            const float* __restrict__ Wq2,
                            const float* __restrict__ Wk2,
                            const float* __restrict__ Wv,
                            unsigned short* __restrict__ ho,
                            unsigned short* __restrict__ so,
                            unsigned short* __restrict__ wcat4,
                            unsigned short* __restrict__ wtv) {
    __shared__ float tile[32][33];
    int bid = blockIdx.x;
    int t = threadIdx.x;
    if (bid < 16384) {
        const float* in = (bid >> 13) ? s : h;
        unsigned short* out = (bid >> 13) ? so : ho;
        size_t i = (((size_t)(bid & 8191)) * 256 + t) * 4;
        float4 f = *(const float4*)(in + i);
        ushort4 o;
        o.x = f2bf(f.x); o.y = f2bf(f.y); o.z = f2bf(f.z); o.w = f2bf(f.w);
        *(ushort4*)(out + i) = o;
        return;
    }
    int bid2 = bid - 16384;
    int z = bid2 >> 10, tl = bid2 & 1023;
    int bx = tl & 31, by = tl >> 5;
    const float* W; unsigned short* Wt;
    switch (z) {
        case 0: W = Wq;  Wt = wcat4;                 break;
        case 1: W = Wk;  Wt = wcat4 + 1024 * 1024;   break;
        case 2: W = Wq2; Wt = wcat4 + 2048 * 1024;   break;
        case 3: W = Wk2; Wt = wcat4 + 3072 * 1024;   break;
        default:W = Wv;  Wt = wtv;                   break;
    }
    int tx = t & 31, ty = t >> 5;
    int col = bx * 32 + tx;
    for (int i = 0; i < 32; i += 8)
        tile[ty + i][tx] = W[(size_t)(by * 32 + ty + i) * Dn + col];
    __syncthreads();
    int ok = by * 32 + tx;
    for (int i = 0; i < 32; i += 8)
        Wt[(size_t)(bx * 32 + ty + i) * Kn + ok] = f2bf(tile[tx][ty + i]);
}

// ---------------- shared GEMM mainloop (128x128 tile, BK=64) ------
__device__ __forceinline__ void gemm_mainloop(const unsigned short* __restrict__ A,
                                              const unsigned short* __restrict__ Bt,
                                              unsigned short* As, unsigned short* Bs,
                                              int m0, int n0, f32x4 acc[4][4]) {
    int t = threadIdx.x;
    int lane = t & 63, wave = t >> 6;
    int wm = (wave >> 1) * 64, wn = (wave & 1) * 64;
    int lrow = lane & 15, lquad = lane >> 4;

    int srow = t >> 3;
    int sc8 = ((t & 7) ^ (srow & 7)) * 8;
    const unsigned short* ap = A  + (size_t)(m0 + srow) * Kn + sc8;
    const unsigned short* bp = Bt + (size_t)(n0 + srow) * Kn + sc8;
    int rph = lrow & 7;

    for (int k0 = 0; k0 < Kn; k0 += 64) {
        for (int s = 0; s < 4; s++) {
            gload_lds16(&As[(t + 256 * s) * 8], ap + (size_t)(32 * s) * Kn + k0);
            gload_lds16(&Bs[(t + 256 * s) * 8], bp + (size_t)(32 * s) * Kn + k0);
        }
        __syncthreads();
        for (int kk = 0; kk < 2; kk++) {
            bf16x8 af[4], bfr[4];
            for (int i = 0; i < 4; i++)
                af[i] = *(const bf16x8*)&As[(wm + i * 16 + lrow) * 64 + ((kk * 4 + lquad) ^ rph) * 8];
            for (int j = 0; j < 4; j++)
                bfr[j] = *(const bf16x8*)&Bs[(wn + j * 16 + lrow) * 64 + ((kk * 4 + lquad) ^ rph) * 8];
            for (int i = 0; i < 4; i++)
                for (int j = 0; j < 4; j++)
                    acc[i][j] = __builtin_amdgcn_mfma_f32_16x16x32_bf16(af[i], bfr[j], acc[i][j], 0, 0, 0);
        }
        __syncthreads();
    }
}

// ---- all 5 projections in ONE dispatch (2560 linearized blocks) ----
__launch_bounds__(256, 3)
__global__ void gemm_all_kernel(const unsigned short* __restrict__ hb,
                                const unsigned short* __restrict__ sb,
                                const unsigned short* __restrict__ wcat4,
                                const unsigned short* __restrict__ wtv,
                                const float* __restrict__ bq,
                                const float* __restrict__ bk,
                                const float* __restrict__ bq2,
                                const float* __restrict__ bk2,
                                const float* __restrict__ bv,
                                unsigned short* __restrict__ qbuf,
                                unsigned short* __restrict__ kbuf,
                                unsigned short* __restrict__ q2buf,
                                unsigned short* __restrict__ k2buf,
                                unsigned short* __restrict__ vtbuf) {
    __shared__ __align__(16) unsigned short As[128 * 64];
    __shared__ __align__(16) unsigned short Bs[128 * 64];
    int bid = blockIdx.x;
    int t = threadIdx.x;
    int lane = t & 63, wave = t >> 6;
    int wm = (wave >> 1) * 64, wn = (wave & 1) * 64;
    int lrow = lane & 15, lquad = lane >> 4;
    f32x4 acc[4][4] = {};

    if (bid < 2048) {
        int n0 = (bid & 31) * 128, m0 = (bid >> 5) * 128;
        int region = n0 >> 10;
        const unsigned short* A = (region == 3) ? sb : hb;
        gemm_mainloop(A, wcat4, As, Bs, m0, n0, acc);

        const float* bp = region == 0 ? bq : region == 1 ? bk : region == 2 ? bq2 : bk2;
        unsigned short* dp = region == 0 ? qbuf : region == 1 ? kbuf : region == 2 ? q2buf : k2buf;
        float sc = (region == 0 || region == 2) ? 0.125f : 1.0f;
        for (int j = 0; j < 4; j++) {
            int gn = (n0 & 1023) + wn + j * 16 + lrow;
            float bv_ = bp[gn];
            int h = gn >> 6, hd = gn & 63;
            for (int i = 0; i < 4; i++)
                for (int r = 0; r < 4; r++) {
                    int gm = m0 + wm + i * 16 + lquad * 4 + r;
                    int b = gm >> 10, ll = gm & 1023;
                    dp[((size_t)(b * Hn + h) * Ln + ll) * HDn + hd] = f2bf((acc[i][j][r] + bv_) * sc);
                }
        }
    } else {
        int b2 = bid - 2048;
        int n0 = (b2 & 63) * 128;     // token tile
        int m0 = (b2 >> 6) * 128;     // channel tile
        gemm_mainloop(wtv, hb, As, Bs, m0, n0, acc);

        for (int j = 0; j < 4; j++) {
            int gn = n0 + wn + j * 16 + lrow;     // token
            int b = gn >> 10, l = gn & 1023;
            for (int i = 0; i < 4; i++)
                for (int r = 0; r < 4; r++) {
                    int gm = m0 + wm + i * 16 + lquad * 4 + r;   // channel
                    int h = gm >> 6, hd = gm & 63;
                    vtbuf[((size_t)(b * Hn + h) * HDn + hd) * Ln + l] = f2bf(acc[i][j][r] + bv[gm]);
                }
        }
    }
}

// ---------------- flash attention, one-pass, register-resident P ---
// Computes S^T = K·Q^T so exp(S^T) (C-layout: row=key=quad*4+r,
// col=qrow=lane&15) IS the B-operand fragment of mfma_16x16x16
// (k=quad*4+j, n=lane&15): P never touches LDS. PV: O^T = V^T · P.
// Output C-layout rows=hd -> float4 stores.
__launch_bounds__(256, 3)
__global__ void attn_kernel(const unsigned short* __restrict__ qb,
                            const unsigned short* __restrict__ kb,
                            const unsigned short* __restrict__ q2b,
                            const unsigned short* __restrict__ k2b,
                            const unsigned short* __restrict__ vtb,
                            const float* __restrict__ mask,
                            float* __restrict__ out) {
    __shared__ __align__(16) unsigned short Ks[64 * 64];
    __shared__ __align__(16) unsigned short K2s[64 * 64];
    __shared__ __align__(16) unsigned short VTs[64 * 64];

    int bh = blockIdx.x;
    int qt = blockIdx.y;
    int b = bh >> 4;
    int t = threadIdx.x;
    int lane = t & 63, wave = t >> 6;
    int lrow = lane & 15, quad = lane >> 4;
    int qbase = qt * 128 + wave * 32;

    // Q/Q2 fragments (used as 2nd MFMA operand: n=lane&15=qrow, k=hd)
    bf16x8 qf[2][2], q2f[2][2];
    for (int rt = 0; rt < 2; rt++)
        for (int kk = 0; kk < 2; kk++) {
            size_t off = ((size_t)bh * Ln + qbase + rt * 16 + lrow) * HDn + kk * 32 + quad * 8;
            qf[rt][kk]  = *(const bf16x8*)(qb + off);
            q2f[rt][kk] = *(const bf16x8*)(q2b + off);
        }

    f32x4 O[4][2] = {};          // [hd-block][rt], C-layout rows=hd
    float lsum[2] = {0.f, 0.f};  // per-lane partial (keys quad*4+r, col qrow)

    int srow = t >> 3;
    int sc8 = ((t & 7) ^ (srow & 7)) * 8;
    const float* maskb = mask + (size_t)b * Ln;
    int rph = lrow & 7;

    for (int kt = 0; kt < 16; kt++) {
        int key0 = kt * 64;
        gload_lds16(&Ks[t * 8],          kb  + ((size_t)bh * Ln + key0 + srow) * HDn + sc8);
        gload_lds16(&Ks[(t + 256) * 8],  kb  + ((size_t)bh * Ln + key0 + 32 + srow) * HDn + sc8);
        gload_lds16(&K2s[t * 8],         k2b + ((size_t)bh * Ln + key0 + srow) * HDn + sc8);
        gload_lds16(&K2s[(t + 256) * 8], k2b + ((size_t)bh * Ln + key0 + 32 + srow) * HDn + sc8);
        gload_lds16(&VTs[t * 8],         vtb + ((size_t)bh * HDn + srow) * Ln + key0 + sc8);
        gload_lds16(&VTs[(t + 256) * 8], vtb + ((size_t)bh * HDn + 32 + srow) * Ln + key0 + sc8);
        __syncthreads();

        // S^T init with mask (rows = keys): float4 per key-block
        f32x4 SJ[4][2];
        for (int j = 0; j < 4; j++) {
            float4 mk = *(const float4*)(maskb + key0 + j * 16 + quad * 4);
            SJ[j][0] = (f32x4){mk.x, mk.y, mk.z, mk.w};
            SJ[j][1] = SJ[j][0];
        }
        // S^T = K·Q^T + K2·Q2^T (operands swapped vs S)
        for (int kk = 0; kk < 2; kk++) {
            for (int j = 0; j < 4; j++) {
                bf16x8 kf = *(const bf16x8*)&Ks[(j * 16 + lrow) * 64 + ((kk * 4 + quad) ^ rph) * 8];
                SJ[j][0] = __builtin_amdgcn_mfma_f32_16x16x32_bf16(kf, qf[0][kk], SJ[j][0], 0, 0, 0);
                SJ[j][1] = __builtin_amdgcn_mfma_f32_16x16x32_bf16(kf, qf[1][kk], SJ[j][1], 0, 0, 0);
            }
            for (int j = 0; j < 4; j++) {
                bf16x8 k2 = *(const bf16x8*)&K2s[(j * 16 + lrow) * 64 + ((kk * 4 + quad) ^ rph) * 8];
                SJ[j][0] = __builtin_amdgcn_mfma_f32_16x16x32_bf16(k2, q2f[0][kk], SJ[j][0], 0, 0, 0);
                SJ[j][1] = __builtin_amdgcn_mfma_f32_16x16x32_bf16(k2, q2f[1][kk], SJ[j][1], 0, 0, 0);
            }
        }

        // P = exp(S^T) in registers; per-lane partial denominators
        s16x4 P[4][2];
        for (int j = 0; j < 4; j++)
            for (int rt = 0; rt < 2; rt++)
                for (int r = 0; r < 4; r++) {
                    float e = __expf(SJ[j][rt][r]);
                    lsum[rt] += e;
                    P[j][rt][r] = (short)f2bf(e);
                }

        // O^T += V^T · P  (A-frag of V^T from LDS, P as B-operand)
        for (int mb = 0; mb < 4; mb++)
            for (int j = 0; j < 4; j++) {
                bf16x4 va = *(const bf16x4*)&VTs[(mb * 16 + lrow) * 64 +
                              ((2 * j + (quad >> 1)) ^ rph) * 8 + (quad & 1) * 4];
                O[mb][0] = mfma16_bf16(va, P[j][0], O[mb][0]);
                O[mb][1] = mfma16_bf16(va, P[j][1], O[mb][1]);
            }
        __syncthreads();
    }

    // denominators: reduce over the 4 quads (lane bits 4,5)
    float rl[2];
    for (int rt = 0; rt < 2; rt++) {
        float s = lsum[rt];
        s += __shfl_xor(s, 16, 64);
        s += __shfl_xor(s, 32, 64);
        rl[rt] = 1.0f / s;
    }

    int h = bh & 15;
    for (int rt = 0; rt < 2; rt++) {
        int ql = qbase + rt * 16 + lrow;
        for (int mb = 0; mb < 4; mb++) {
            float4 o4 = {O[mb][rt][0] * rl[rt], O[mb][rt][1] * rl[rt],
                         O[mb][rt][2] * rl[rt], O[mb][rt][3] * rl[rt]};
            *(float4*)(out + ((size_t)b * Ln + ql) * Dn + h * HDn + mb * 16 + quad * 4) = o4;
        }
    }
}

extern "C" void kernel_launch(void* const* d_in, const int* in_sizes, int n_in,
                              void* d_out, int out_size, void* d_ws, size_t ws_size,
                              hipStream_t stream) {
    const float* hidden = (const float*)d_in[0];
    const float* mask   = (const float*)d_in[1];
    const float* source = (const float*)d_in[2];
    const float* Wq  = (const float*)d_in[3];
    const float* bq  = (const float*)d_in[4];
    const float* Wk  = (const float*)d_in[5];
    const float* bk  = (const float*)d_in[6];
    const float* Wv  = (const float*)d_in[7];
    const float* bv  = (const float*)d_in[8];
    const float* Wq2 = (const float*)d_in[9];
    const float* bq2 = (const float*)d_in[10];
    const float* Wk2 = (const float*)d_in[11];
    const float* bk2 = (const float*)d_in[12];
    float* out = (float*)d_out;

    char* ws = (char*)d_ws;
    const size_t act_sz = (size_t)Mn * Dn * 2;   // 16 MB
    const size_t w_sz   = (size_t)Kn * Dn * 2;   // 2 MB
    unsigned short* hb    = (unsigned short*)ws; ws += act_sz;
    unsigned short* sb    = (unsigned short*)ws; ws += act_sz;
    unsigned short* wcat4 = (unsigned short*)ws; ws += 4 * w_sz;
    unsigned short* wtv   = (unsigned short*)ws; ws += w_sz;
    unsigned short* qbuf  = (unsigned short*)ws; ws += act_sz;
    unsigned short* kbuf  = (unsigned short*)ws; ws += act_sz;
    unsigned short* q2buf = (unsigned short*)ws; ws += act_sz;
    unsigned short* k2buf = (unsigned short*)ws; ws += act_sz;
    unsigned short* vtbuf = (unsigned short*)ws; ws += act_sz;

    // 1) prep: converts + transposes, one dispatch
    prep_kernel<<<21504, 256, 0, stream>>>(hidden, source, Wq, Wk, Wq2, Wk2, Wv,
                                           hb, sb, wcat4, wtv);

    // 2) all 5 projections, one dispatch (BK=64 mainloop)
    gemm_all_kernel<<<2560, 256, 0, stream>>>(hb, sb, wcat4, wtv,
                                              bq, bk, bq2, bk2, bv,
                                              qbuf, kbuf, q2buf, k2buf, vtbuf);

    // 3) attention (Q-tile 128, one-pass softmax, register-resident P)
    dim3 agrid(Bn * Hn, Ln / 128);               // (128, 8)
    attn_kernel<<<agrid, 256, 0, stream>>>(qbuf, kbuf, q2buf, k2buf, vtbuf, mask, out);
}